// Round 15
// baseline (570.437 us; speedup 1.0000x reference)
//
#include <hip/hip_runtime.h>
#include <hip/hip_bf16.h>

#define B_ 4
#define N_ 2048
#define D_ 1024
#define H_ 16
#define HD_ 64
#define MTOT (B_*N_)   // 8192
#define CH_ 32         // scan chunk size
#define NCH_ (N_/CH_)  // 64

typedef __attribute__((ext_vector_type(8))) short short8v;
typedef __attribute__((ext_vector_type(4))) float f32x4;

// fast sigmoid: raw v_rcp_f32 (~1 ulp), avoids IEEE div sequence on the serial chain
__device__ __forceinline__ float fsig(float x){
  return __builtin_amdgcn_rcpf(1.0f + __expf(-x));
}

// ---------------- cast x -> bf16 (vectorized) ----------------
__global__ void k_cast_bf16(const float* __restrict__ in, __hip_bfloat16* __restrict__ out, int n4){
  int i = blockIdx.x*256 + threadIdx.x;
  if (i >= n4) return;
  float4 vv = ((const float4*)in)[i];
  __hip_bfloat16 b0 = __float2bfloat16(vv.x), b1 = __float2bfloat16(vv.y),
                 b2 = __float2bfloat16(vv.z), b3 = __float2bfloat16(vv.w);
  ushort4 o;
  o.x = *(const unsigned short*)&b0; o.y = *(const unsigned short*)&b1;
  o.z = *(const unsigned short*)&b2; o.w = *(const unsigned short*)&b3;
  ((ushort4*)out)[i] = o;
}

// ---------------- transpose + cast: out[c][r] = in[r][c] ----------------
__global__ void k_transpose_cast(const float* __restrict__ in, __hip_bfloat16* __restrict__ out,
                                 int R, int C){
  __shared__ float tile[64][65];
  int r0 = blockIdx.y*64, c0 = blockIdx.x*64;
  int tid = threadIdx.x;
  #pragma unroll
  for (int i=0;i<16;i++){ int idx = tid + i*256; int rr = idx>>6, cc = idx&63;
    tile[rr][cc] = in[(size_t)(r0+rr)*C + (c0+cc)]; }
  __syncthreads();
  #pragma unroll
  for (int i=0;i<16;i++){ int idx = tid + i*256; int rr = idx>>6, cc = idx&63;
    out[(size_t)(c0+rr)*R + (r0+cc)] = __float2bfloat16(tile[cc][rr]); }
}

// ---------------- pack gate/lr weights: WgL[128][1024] = [Wg1^T ; Wlr^T ; 0] ----------------
__global__ void k_prep_wgl(const float* __restrict__ Wg1, const float* __restrict__ Wlr,
                           __hip_bfloat16* __restrict__ WgL){
  int idx = blockIdx.x*256 + threadIdx.x;   // 0..131071
  int r = idx >> 10, d = idx & 1023;
  float v = 0.f;
  if (r < 64) v = Wg1[(size_t)d*64 + r];
  else if (r < 80) v = Wlr[(size_t)d*16 + (r-64)];
  WgL[idx] = __float2bfloat16(v);
}

// ---------------- post: proj[8192][128] -> t1 bf16 (cols 0-63), lr = 0.01*sigmoid (cols 64-79) ----
__global__ void k_post_gl(const float* __restrict__ proj, __hip_bfloat16* __restrict__ t1,
                          float* __restrict__ lrout){
  int m = blockIdx.x*4 + (threadIdx.x>>6);
  int e = threadIdx.x & 63;
  float val = proj[(size_t)m*128 + e];
  t1[(size_t)m*64 + e] = __float2bfloat16(val);
  if (e < 16){
    float s = proj[(size_t)m*128 + 64 + e];
    lrout[(size_t)m*16 + e] = 0.01f*fsig(s);
  }
}

// ---------------- async global->LDS helper (16B per lane, dest = base + lane*16) ----------------
__device__ __forceinline__ void gl2lds16(const void* g, void* l){
  __builtin_amdgcn_global_load_lds((const __attribute__((address_space(1))) void*)g,
                                   (__attribute__((address_space(3))) void*)l, 16, 0, 0);
}

// ---------------- bf16 MFMA GEMM with global_load_lds staging ----------------
// LAYOUT 0: C[m*N+col]. LAYOUT 1: scatter [b][h][t][e]. LAYOUT 2: fused QKV (N=3072).
template<int ACT, int LAYOUT>
__global__ __launch_bounds__(256,2) void k_gemm_bt2(
    const __hip_bfloat16* __restrict__ A, const __hip_bfloat16* __restrict__ BT,
    float* __restrict__ C, int M, int N, int K)
{
  __shared__ short As[128*32];
  __shared__ short Bs[128*32];
  const int n0 = blockIdx.x*128, m0 = blockIdx.y*128;
  const int tid = threadIdx.x, lane = tid & 63, wid = tid >> 6;
  const int wm = wid >> 1, wn = wid & 1;
  const short* Aps = (const short*)A;
  const short* Bps = (const short*)BT;
  f32x4 acc[4][4] = {};
  const int srow = wid*32 + (lane>>2);
  const int scol = (lane&3)*8;
  const size_t aoff0 = (size_t)(m0+srow)*K + scol;
  const size_t boff0 = (size_t)(n0+srow)*K + scol;
  short* lA = As + wid*1024;
  short* lB = Bs + wid*1024;
  const int row = lane & 15, kq = (lane >> 4)*8;
  for (int kk = 0; kk < K; kk += 32) {
    __syncthreads();
    gl2lds16(Aps + aoff0 + kk,                 lA);
    gl2lds16(Aps + aoff0 + (size_t)16*K + kk,  lA + 512);
    gl2lds16(Bps + boff0 + kk,                 lB);
    gl2lds16(Bps + boff0 + (size_t)16*K + kk,  lB + 512);
    __syncthreads();
    short8v af[4], bfr[4];
    #pragma unroll
    for (int i=0;i<4;i++) af[i]  = *(const short8v*)(As + (wm*64 + i*16 + row)*32 + kq);
    #pragma unroll
    for (int j=0;j<4;j++) bfr[j] = *(const short8v*)(Bs + (wn*64 + j*16 + row)*32 + kq);
    #pragma unroll
    for (int i=0;i<4;i++)
      #pragma unroll
      for (int j=0;j<4;j++)
        acc[i][j] = __builtin_amdgcn_mfma_f32_16x16x32_bf16(af[i], bfr[j], acc[i][j], 0, 0, 0);
  }
  #pragma unroll
  for (int i=0;i<4;i++){
    #pragma unroll
    for (int j=0;j<4;j++){
      int col = n0 + wn*64 + j*16 + (lane & 15);
      #pragma unroll
      for (int qq=0; qq<4; ++qq){
        int rowg = m0 + wm*64 + i*16 + (lane>>4)*4 + qq;
        float val = acc[i][j][qq];
        if (LAYOUT==0) {
          if (ACT==1) val = val*fsig(val);
          C[(size_t)rowg*N + col] = val;
        } else if (LAYOUT==1) {
          if (ACT==1) val = val*fsig(val);
          size_t oidx = ((((size_t)(rowg>>11))*16 + (col>>6))*(size_t)N_ + (size_t)(rowg & 2047))*64
                        + (size_t)(col & 63);
          C[oidx] = val;
        } else {
          const int t3 = col >> 10, cc2 = col & 1023;
          if (t3 < 2) val = val*fsig(val);   // silu on q,k; none on v
          size_t oidx = (size_t)t3*((size_t)MTOT*D_)
                      + ((((size_t)(rowg>>11))*16 + (cc2>>6))*(size_t)N_ + (size_t)(rowg & 2047))*64
                      + (size_t)(cc2 & 63);
          C[oidx] = val;
        }
      }
    }
  }
}

// ---------------- helpers for chunked scan ----------------
__device__ __forceinline__ unsigned short bfr16(float x){
  __hip_bfloat16 b = __float2bfloat16(x);
  return *(unsigned short*)&b;
}
__device__ __forceinline__ short8v cvt_frag(const float4 a, const float4 c){
  short8v r;
  r[0]=(short)bfr16(a.x); r[1]=(short)bfr16(a.y); r[2]=(short)bfr16(a.z); r[3]=(short)bfr16(a.w);
  r[4]=(short)bfr16(c.x); r[5]=(short)bfr16(c.y); r[6]=(short)bfr16(c.z); r[7]=(short)bfr16(c.w);
  return r;
}

// ---------------- chunked fast-weight scan v12: CH=32 (amortize per-phase overhead) ----------------
// 3 barriers per 32 tokens (was 6). A: 2 t-tiles of products + 4 GKK tiles + 3 GQK tiles.
// B: wave0 lanes<16, 32 tokens with eager corrections (full 32-wide Gram rows, 3-deep reg pipe).
// O: 2 (t,e) pairs/thread, 32-corr masked. C: rank-32 update from LDS kS + mirror rewrite.
// v/lr staged to LDS by waves1-3 (loads issued during B window, written after bar2).
__global__ __launch_bounds__(256,1) void k_scan12(
    const float* __restrict__ q, const float* __restrict__ k, const float* __restrict__ v,
    const float* __restrict__ lr, const float* __restrict__ w1i, const float* __restrict__ w3i,
    float* __restrict__ so)
{
  const int blk = blockIdx.x;            // 0..255
  const int bh  = blk >> 2;              // b*16+h
  const int sl  = blk & 3;               // e-slab
  const int b = bh >> 4, h = bh & 15;
  const int e0 = sl*16;
  const int tid = threadIdx.x, lane = tid & 63, wid = tid >> 6;
  const int tA = lane & 15, g = lane >> 4;
  const int ks8 = g*8;

  __shared__ __align__(16) __hip_bfloat16 Wb1[16*64];   // mirror [e][d], XOR-swizzled
  __shared__ __align__(16) __hip_bfloat16 Wb3[16*64];
  __shared__ __align__(16) float KW1e[16*32], KW3e[16*32];  // [e][t], swizzled per 16-half
  __shared__ __align__(16) float QW1[32*16], QW3[32*16];    // [t][e]
  __shared__ __align__(16) float GKK[32*32], GQK[32*32];    // [t][s]
  __shared__ __align__(16) float C13[32*16*2];              // [s][e][{c1,c3}]
  __shared__ __align__(16) float kS[32][68];                // chunk k rows fp32 (+4 pad)
  __shared__ __align__(16) float vS[32*16];                 // [t][e]
  __shared__ float lrS[32];

  const int we = tid & 15;
  const int wd = (tid >> 4) * 4;
  float w1r[4], w3r[4];
  {
    const float* w1p = w1i + (size_t)h*HD_*HD_ + e0 + we;
    const float* w3p = w3i + (size_t)h*HD_*HD_ + e0 + we;
    #pragma unroll
    for (int j=0;j<4;j++){ w1r[j] = w1p[(size_t)(wd+j)*64]; w3r[j] = w3p[(size_t)(wd+j)*64]; }
  }
  const int mir_off = we*128 + ((wd*2) ^ ((we&7)<<4));
  auto write_mirrors = [&](){
    uint2 p1, p3;
    p1.x = (unsigned)bfr16(w1r[0]) | ((unsigned)bfr16(w1r[1])<<16);
    p1.y = (unsigned)bfr16(w1r[2]) | ((unsigned)bfr16(w1r[3])<<16);
    p3.x = (unsigned)bfr16(w3r[0]) | ((unsigned)bfr16(w3r[1])<<16);
    p3.y = (unsigned)bfr16(w3r[2]) | ((unsigned)bfr16(w3r[3])<<16);
    *(uint2*)((char*)Wb1 + mir_off) = p1;
    *(uint2*)((char*)Wb3 + mir_off) = p3;
  };
  write_mirrors();

  const float* kfb = k + (size_t)bh*N_*64;
  const float* qfb = q + (size_t)bh*N_*64;
  const float* vfb = v + (size_t)bh*N_*64;
  const float* lrp = lr + ((size_t)b*N_)*16 + h;
  float* sob = so + (((size_t)b*N_)*16 + h)*64 + e0;

  auto mir_read = [&](const __hip_bfloat16* Wm, int m)->short8v{
    return *(const short8v*)((const char*)Wm + tA*128 + (((m*32+ks8)*2) ^ ((tA&7)<<4)));
  };

  // prefetch regs: fK (waves1,3): k tiles T0,T1; fQ (waves2,3): q tiles U0,U1
  float4 fK0,fK1,fK2,fK3,fK4,fK5,fK6,fK7;
  float4 fQ0,fQ1,fQ2,fQ3,fQ4,fQ5,fQ6,fQ7;
  float  vPr0,vPr1,vPr2,vPr3;      // waves1,2: v values (4/lane)
  float  lrPr = 0.f;               // wave3 lanes<32

  auto load_kq = [&](int t0n){
    if (wid==1 || wid==3){
      const float* kr0 = kfb + (size_t)(t0n+tA)*64;
      const float* kr1 = kfb + (size_t)(t0n+16+tA)*64;
      fK0 = *(const float4*)(kr0+ks8);    fK1 = *(const float4*)(kr0+ks8+4);
      fK2 = *(const float4*)(kr0+32+ks8); fK3 = *(const float4*)(kr0+32+ks8+4);
      fK4 = *(const float4*)(kr1+ks8);    fK5 = *(const float4*)(kr1+ks8+4);
      fK6 = *(const float4*)(kr1+32+ks8); fK7 = *(const float4*)(kr1+32+ks8+4);
    }
    if (wid==2 || wid==3){
      const float* qr0 = qfb + (size_t)(t0n+tA)*64;
      const float* qr1 = qfb + (size_t)(t0n+16+tA)*64;
      fQ0 = *(const float4*)(qr0+ks8);    fQ1 = *(const float4*)(qr0+ks8+4);
      fQ2 = *(const float4*)(qr0+32+ks8); fQ3 = *(const float4*)(qr0+32+ks8+4);
      fQ4 = *(const float4*)(qr1+ks8);    fQ5 = *(const float4*)(qr1+ks8+4);
      fQ6 = *(const float4*)(qr1+32+ks8); fQ7 = *(const float4*)(qr1+32+ks8+4);
    }
    if (wid==1){
      #pragma unroll
      for (int i=0;i<4;i++){
        int idx = lane + 64*i;          // 0..255 -> t 0..15
        ((float*)&vPr0)[0]; // no-op
      }
      vPr0 = vfb[(size_t)(t0n + ((lane+  0)>>4))*64 + e0 + ((lane+  0)&15)];
      vPr1 = vfb[(size_t)(t0n + ((lane+ 64)>>4))*64 + e0 + ((lane+ 64)&15)];
      vPr2 = vfb[(size_t)(t0n + ((lane+128)>>4))*64 + e0 + ((lane+128)&15)];
      vPr3 = vfb[(size_t)(t0n + ((lane+192)>>4))*64 + e0 + ((lane+192)&15)];
    } else if (wid==2){
      vPr0 = vfb[(size_t)(t0n + 16 + ((lane+  0)>>4))*64 + e0 + ((lane+  0)&15)];
      vPr1 = vfb[(size_t)(t0n + 16 + ((lane+ 64)>>4))*64 + e0 + ((lane+ 64)&15)];
      vPr2 = vfb[(size_t)(t0n + 16 + ((lane+128)>>4))*64 + e0 + ((lane+128)&15)];
      vPr3 = vfb[(size_t)(t0n + 16 + ((lane+192)>>4))*64 + e0 + ((lane+192)&15)];
    } else if (wid==3 && lane<32){
      lrPr = lrp[(size_t)(t0n+lane)*16];
    }
  };
  auto store_vlr = [&](){
    if (wid==1){
      vS[lane+  0] = vPr0; vS[lane+ 64] = vPr1; vS[lane+128] = vPr2; vS[lane+192] = vPr3;
    } else if (wid==2){
      vS[256+lane+  0] = vPr0; vS[256+lane+ 64] = vPr1; vS[256+lane+128] = vPr2; vS[256+lane+192] = vPr3;
    } else if (wid==3 && lane<32){
      lrS[lane] = lrPr;
    }
  };

  // ---- prologue: chunk 0 ----
  load_kq(0);
  store_vlr();
  __syncthreads();

  #pragma unroll 1
  for (int c = 0; c < NCH_; ++c) {
    const int t0 = c*CH_;

    // ---- phase A ----
    if (wid == 1) {
      // kS stores (fp32 k rows for phase C)
      *(float4*)&kS[tA][ks8]         = fK0;  *(float4*)&kS[tA][ks8+4]       = fK1;
      *(float4*)&kS[tA][32+ks8]      = fK2;  *(float4*)&kS[tA][32+ks8+4]    = fK3;
      *(float4*)&kS[16+tA][ks8]      = fK4;  *(float4*)&kS[16+tA][ks8+4]    = fK5;
      *(float4*)&kS[16+tA][32+ks8]   = fK6;  *(float4*)&kS[16+tA][32+ks8+4] = fK7;
      short8v a0 = cvt_frag(fK0,fK1), a1f = cvt_frag(fK2,fK3);
      short8v b0 = cvt_frag(fK4,fK5), b1f = cvt_frag(fK6,fK7);
      const int slot = (g*4) ^ (((tA>>1)&3)<<2);
      f32x4 acc = {};
      acc = __builtin_amdgcn_mfma_f32_16x16x32_bf16(a0, mir_read(Wb1,0), acc, 0,0,0);
      acc = __builtin_amdgcn_mfma_f32_16x16x32_bf16(a1f, mir_read(Wb1,1), acc, 0,0,0);
      *(f32x4*)&KW1e[tA*32 + slot] = acc;
      f32x4 ac2 = {};
      ac2 = __builtin_amdgcn_mfma_f32_16x16x32_bf16(b0, mir_read(Wb1,0), ac2, 0,0,0);
      ac2 = __builtin_amdgcn_mfma_f32_16x16x32_bf16(b1f, mir_read(Wb1,1), ac2, 0,0,0);
      *(f32x4*)&KW1e[tA*32 + 16 + slot] = ac2;
      f32x4 ac3 = {};
      ac3 = __builtin_amdgcn_mfma_f32_16x16x32_bf16(a0, mir_read(Wb3,0), ac3, 0,0,0);
      ac3 = __builtin_amdgcn_mfma_f32_16x16x32_bf16(a1f, mir_read(Wb3,1), ac3, 0,0,0);
      *(f32x4*)&KW3e[tA*32 + slot] = ac3;
      f32x4 ac4 = {};
      ac4 = __builtin_amdgcn_mfma_f32_16x16x32_bf16(b0, mir_read(Wb3,0), ac4, 0,0,0);
      ac4 = __builtin_amdgcn_mfma_f32_16x16x32_bf16(b1f, mir_read(Wb3,1), ac4, 0,0,0);
      *(f32x4*)&KW3e[tA*32 + 16 + slot] = ac4;
    } else if (wid == 2) {
      short8v a0 = cvt_frag(fQ0,fQ1), a1f = cvt_frag(fQ2,fQ3);
      short8v b0 = cvt_frag(fQ4,fQ5), b1f = cvt_frag(fQ6,fQ7);
      f32x4 acc = {};
      acc = __builtin_amdgcn_mfma_f32_16x16x32_bf16(a0, mir_read(Wb1,0), acc, 0,0,0);
      acc = __builtin_amdgcn_mfma_f32_16x16x32_bf16(a1f, mir_read(Wb1,1), acc, 0,0,0);
      #pragma unroll
      for (int qq=0;qq<4;++qq) QW1[(g*4+qq)*16 + tA] = acc[qq];
      f32x4 ac2 = {};
      ac2 = __builtin_amdgcn_mfma_f32_16x16x32_bf16(b0, mir_read(Wb1,0), ac2, 0,0,0);
      ac2 = __builtin_amdgcn_mfma_f32_16x16x32_bf16(b1f, mir_read(Wb1,1), ac2, 0,0,0);
      #pragma unroll
      for (int qq=0;qq<4;++qq) QW1[(16+g*4+qq)*16 + tA] = ac2[qq];
      f32x4 ac3 = {};
      ac3 = __builtin_amdgcn_mfma_f32_16x16x32_bf16(a0, mir_read(Wb3,0), ac3, 0,0,0);
      ac3 = __builtin_amdgcn_mfma_f32_16x16x32_bf16(a1f, mir_read(Wb3,1), ac3, 0,0,0);
      #pragma unroll
      for (int qq=0;qq<4;++qq) QW3[(g*4+qq)*16 + tA] = ac3[qq];
      f32x4 ac4 = {};
      ac4 = __builtin_amdgcn_mfma_f32_16x16x32_bf16(b0, mir_read(Wb3,0), ac4, 0,0,0);
      ac4 = __builtin_amdgcn_mfma_f32_16x16x32_bf16(b1f, mir_read(Wb3,1), ac4, 0,0,0);
      #pragma unroll
      for (int qq=0;qq<4;++qq) QW3[(16+g*4+qq)*16 + tA] = ac4[qq];
    } else if (wid == 3) {
      short8v ka0 = cvt_frag(fK0,fK1), ka1 = cvt_frag(fK2,fK3);
      short8v kb0 = cvt_frag(fK4,fK5), kb1 = cvt_frag(fK6,fK7);
      short8v qa0 = cvt_frag(fQ0,fQ1), qa1 = cvt_frag(fQ2,fQ3);
      short8v qb0 = cvt_frag(fQ4,fQ5), qb1 = cvt_frag(fQ6,fQ7);
      // GKK tiles (tT,sT): (0,0),(0,1),(1,0),(1,1)
      {
        f32x4 t00 = {}, t01 = {}, t10 = {}, t11 = {};
        t00 = __builtin_amdgcn_mfma_f32_16x16x32_bf16(ka0, ka0, t00, 0,0,0);
        t00 = __builtin_amdgcn_mfma_f32_16x16x32_bf16(ka1, ka1, t00, 0,0,0);
        t01 = __builtin_amdgcn_mfma_f32_16x16x32_bf16(ka0, kb0, t01, 0,0,0);
        t01 = __builtin_amdgcn_mfma_f32_16x16x32_bf16(ka1, kb1, t01, 0,0,0);
        t10 = __builtin_amdgcn_mfma_f32_16x16x32_bf16(kb0, ka0, t10, 0,0,0);
        t10 = __builtin_amdgcn_mfma_f32_16x16x32_bf16(kb1, ka1, t10, 0,0,0);
        t11 = __builtin_amdgcn_mfma_f32_16x16x32_bf16(kb0, kb0, t11, 0,0,0);
        t11 = __builtin_amdgcn_mfma_f32_16x16x32_bf16(kb1, kb1, t11, 0,0,0);
        #pragma unroll
        for (int qq=0;qq<4;++qq){
          GKK[(g*4+qq)*32 + tA]        = t00[qq];
          GKK[(g*4+qq)*32 + 16 + tA]   = t01[qq];
          GKK[(16+g*4+qq)*32 + tA]     = t10[qq];
          GKK[(16+g*4+qq)*32 + 16+tA]  = t11[qq];
        }
      }
      // GQK tiles (s<=t needed): (0,0),(1,0),(1,1)
      {
        f32x4 u00 = {}, u10 = {}, u11 = {};
        u00 = __builtin_amdgcn_mfma_f32_16x16x32_bf16(qa0, ka0, u00, 0,0,0);
        u00 = __builtin_amdgcn_mfma_f32_16x16x32_bf16(qa1, ka1, u00, 0,0,0);
        u10 = __builtin_amdgcn_mfma_f32_16x16x32_bf16(qb0, ka0, u10, 0,0,0);
        u10 = __builtin_amdgcn_mfma_f32_16x16x32_bf16(qb1, ka1, u10, 0,0,0);
        u11 = __builtin_amdgcn_mfma_f32_16x16x32_bf16(qb0, kb0, u11, 0,0,0);
        u11 = __builtin_amdgcn_mfma_f32_16x16x32_bf16(qb1, kb1, u11, 0,0,0);
        #pragma unroll
        for (int qq=0;qq<4;++qq){
          GQK[(g*4+qq)*32 + tA]        = u00[qq];
          GQK[(16+g*4+qq)*32 + tA]     = u10[qq];
          GQK[(16+g*4+qq)*32 + 16+tA]  = u11[qq];
        }
      }
    }
    __syncthreads();   // bar1: A results + vS/lrS visible

    // ---- phase B window ----
    const int tn0 = ((c+1 < NCH_) ? c+1 : c) * CH_;
    if (wid >= 1) {
      load_kq(tn0);    // prefetch next chunk; loads fly under wave0's B
    } else if (lane < 16) {
      float a1[32], a3[32];
      const int swr = ((lane>>1)&3)<<2;
      #pragma unroll
      for (int X=0;X<2;X++)
        #pragma unroll
        for (int i2=0;i2<4;i2++){
          f32x4 x1 = *(const f32x4*)&KW1e[lane*32 + X*16 + ((i2*4) ^ swr)];
          f32x4 x3 = *(const f32x4*)&KW3e[lane*32 + X*16 + ((i2*4) ^ swr)];
          a1[X*16+i2*4+0]=x1[0]; a1[X*16+i2*4+1]=x1[1]; a1[X*16+i2*4+2]=x1[2]; a1[X*16+i2*4+3]=x1[3];
          a3[X*16+i2*4+0]=x3[0]; a3[X*16+i2*4+1]=x3[1]; a3[X*16+i2*4+2]=x3[2]; a3[X*16+i2*4+3]=x3[3];
        }
      f32x4 grow[3][8];
      #pragma unroll
      for (int i2=0;i2<8;i2++){
        grow[0][i2] = *(const f32x4*)&GKK[ 0 + i2*4];
        grow[1][i2] = *(const f32x4*)&GKK[32 + i2*4];
        grow[2][i2] = *(const f32x4*)&GKK[64 + i2*4];
      }
      #pragma unroll
      for (int t = 0; t < CH_; ++t) {
        const float h1 = a1[t], h3 = a3[t];
        const float sg = fsig(h1);
        const float s1 = h1*sg;
        const float er = fmaf(s1, h3, -vS[t*16+lane]);
        const float ds = sg*fmaf(h1, 1.0f - sg, 1.0f);
        const float lt = lrS[t];
        float2 cc; cc.x = lt*(er*h3*ds); cc.y = lt*(er*s1);
        *(float2*)&C13[(t*16+lane)*2] = cc;
        #pragma unroll
        for (int t2 = t+1; t2 < CH_; ++t2) {
          const float gg = grow[t%3][t2>>2][t2&3];
          a1[t2] = fmaf(-gg, cc.x, a1[t2]);
          a3[t2] = fmaf(-gg, cc.y, a3[t2]);
        }
        if (t + 3 < CH_) {
          #pragma unroll
          for (int i2=0;i2<8;i2++) grow[(t+3)%3][i2] = *(const f32x4*)&GKK[(t+3)*32 + i2*4];
        }
      }
    }
    __syncthreads();   // bar2: C13 visible

    // ---- phase O: 2 (t,e) pairs per thread; masked full unroll ----
    {
      const int oe = tid & 15, otb = tid >> 4;
      float c1r[32], c3r[32];
      #pragma unroll
      for (int s=0;s<CH_;++s){
        float2 cc = *(const float2*)&C13[(s*16+oe)*2];
        c1r[s]=cc.x; c3r[s]=cc.y;
      }
      #pragma unroll
      for (int pr=0; pr<2; ++pr){
        const int ot = otb + pr*16;
        float o1 = QW1[ot*16+oe], o3 = QW3[ot*16+oe];
        float gq[32];
        #pragma unroll
        for (int i2=0;i2<8;i2++){
          f32x4 a = *(const f32x4*)&GQK[ot*32 + i2*4];
          gq[i2*4]=a[0]; gq[i2*4+1]=a[1]; gq[i2*4+2]=a[2]; gq[i2*4+3]=a[3];
        }
        #pragma unroll
        for (int s=0;s<CH_;++s){
          const float gg = (s <= ot) ? gq[s] : 0.0f;
          o1 = fmaf(-gg, c1r[s], o1);
          o3 = fmaf(-gg, c3r[s], o3);
        }
        sob[(size_t)(t0+ot)*(H_*HD_) + oe] = (o1*fsig(o1))*o3;
      }
    }

    // ---- phase C: rank-32 W update (k rows from LDS) + mirror ----
    #pragma unroll
    for (int s = 0; s < CH_; ++s) {
      const float2 cc = *(const float2*)&C13[(s*16+we)*2];
      const float4 ks = *(const float4*)&kS[s][wd];
      w1r[0] = fmaf(-ks.x, cc.x, w1r[0]); w1r[1] = fmaf(-ks.y, cc.x, w1r[1]);
      w1r[2] = fmaf(-ks.z, cc.x, w1r[2]); w1r[3] = fmaf(-ks.w, cc.x, w1r[3]);
      w3r[0] = fmaf(-ks.x, cc.y, w3r[0]); w3r[1] = fmaf(-ks.y, cc.y, w3r[1]);
      w3r[2] = fmaf(-ks.z, cc.y, w3r[2]); w3r[3] = fmaf(-ks.w, cc.y, w3r[3]);
    }
    write_mirrors();
    store_vlr();       // v/lr for chunk c+1 (loads landed during B)
    __syncthreads();   // bar3: mirror + vS ready for next A/B
  }
}

// ---------------- grouped RMSNorm * norm_w * sigmoid(gate) -> bf16 y ----------------
__global__ void k_norm_gate(const float* __restrict__ so, const float* __restrict__ gate,
                            const float* __restrict__ nw, __hip_bfloat16* __restrict__ y)
{
  int idx = blockIdx.x*4 + (threadIdx.x>>6);  // (b*N+t)*16+h
  int e = threadIdx.x & 63;
  float o = so[(size_t)idx*64 + e];
  float ss = o*o;
  #pragma unroll
  for (int m=32; m>=1; m>>=1) ss += __shfl_xor(ss, m, 64);
  float rms = rsqrtf(ss*(1.0f/64.0f) + 1e-6f);
  int hh = idx & 15;
  size_t bn = (size_t)(idx >> 4);
  int d = hh*64 + e;
  float g = gate[bn*1024 + d];
  float val = o*rms*nw[d] * fsig(g);
  y[bn*1024 + d] = __float2bfloat16(val);
}

extern "C" void kernel_launch(void* const* d_in, const int* in_sizes, int n_in,
                              void* d_out, int out_size, void* d_ws, size_t ws_size,
                              hipStream_t stream)
{
  const float* x   = (const float*)d_in[0];
  const float* Wq  = (const float*)d_in[1];
  const float* Wk  = (const float*)d_in[2];
  const float* Wv  = (const float*)d_in[3];
  const float* Wo  = (const float*)d_in[4];
  const float* w1i = (const float*)d_in[5];
  const float* w3i = (const float*)d_in[6];
  const float* Wlr = (const float*)d_in[7];
  const float* nw  = (const float*)d_in[8];
  const float* Wg1 = (const float*)d_in[9];
  const float* Wg2 = (const float*)d_in[10];
  float* out = (float*)d_out;

  char* p = (char*)d_ws;
  auto take = [&](size_t bytes)->void*{ void* r = (void*)p; p += (bytes + 255) & ~(size_t)255; return r; };
  __hip_bfloat16* xb    = (__hip_bfloat16*)take((size_t)MTOT*D_*2);
  __hip_bfloat16* WqkvT = (__hip_bfloat16*)take((size_t)3*D_*D_*2);   // [Wq^T ; Wk^T ; Wv^T]
  __hip_bfloat16* Wot   = (__hip_bfloat16*)take((size_t)D_*D_*2);
  __hip_bfloat16* Wg2t  = (__hip_bfloat16*)take((size_t)D_*HD_*2);
  __hip_bfloat16* WgL   = (__hip_bfloat16*)take((size_t)128*D_*2);
  __hip_bfloat16* t1b   = (__hip_bfloat16*)take((size_t)MTOT*HD_*2);
  float* projt = (float*)take((size_t)MTOT*128*4);
  float* qf  = (float*)take((size_t)MTOT*D_*4);   // qf,kf,vf contiguous
  float* kf  = (float*)take((size_t)MTOT*D_*4);
  float* vf  = (float*)take((size_t)MTOT*D_*4);
  float* lrb = (float*)take((size_t)MTOT*H_*4);
  float* sob = (float*)take((size_t)MTOT*D_*4);
  __hip_bfloat16* yb = (__hip_bfloat16*)take((size_t)MTOT*D_*2);
  (void)kf; (void)vf;

  k_cast_bf16<<<MTOT*D_/4/256, 256, 0, stream>>>(x, xb, MTOT*D_/4);
  k_transpose_cast<<<dim3(16,16), 256, 0, stream>>>(Wq, WqkvT,             D_, D_);
  k_transpose_cast<<<dim3(16,16), 256, 0, stream>>>(Wk, WqkvT + D_*D_,     D_, D_);
  k_transpose_cast<<<dim3(16,16), 256, 0, stream>>>(Wv, WqkvT + 2*D_*D_,   D_, D_);
  k_transpose_cast<<<dim3(16,16), 256, 0, stream>>>(Wo, Wot, D_, D_);
  k_transpose_cast<<<dim3(16,1),  256, 0, stream>>>(Wg2, Wg2t, HD_, D_);
  k_prep_wgl<<<512, 256, 0, stream>>>(Wg1, Wlr, WgL);
  // gate bottleneck + lr head in one GEMM: proj = x @ [Wg1 | Wlr | 0]
  k_gemm_bt2<0,0><<<dim3(1,64), 256, 0, stream>>>(xb, WgL, projt, MTOT, 128, D_);
  k_post_gl<<<MTOT/4, 256, 0, stream>>>(projt, t1b, lrb);
  // fused q|k|v projection: one N=3072 GEMM, silu on q,k, scatter to [b][h][t][e]
  k_gemm_bt2<1,2><<<dim3(24,64), 256, 0, stream>>>(xb, WqkvT, qf, MTOT, 3*D_, D_);
  // gate pre-activation into d_out (free scratch until final GEMM)
  k_gemm_bt2<0,0><<<dim3(8,64), 256, 0, stream>>>(t1b, Wg2t, out, MTOT, D_, HD_);
  k_scan12<<<256, 256, 0, stream>>>(qf, kf, vf, lrb, w1i, w3i, sob);
  k_norm_gate<<<MTOT*H_/4, 256, 0, stream>>>(sob, out, nw, yb);
  k_gemm_bt2<0,0><<<dim3(8,64), 256, 0, stream>>>(yb, Wot, out, MTOT, D_, D_);
}

// Round 16
// 497.720 us; speedup vs baseline: 1.1461x; 1.1461x over previous
//
#include <hip/hip_runtime.h>
#include <hip/hip_bf16.h>

#define B_ 4
#define N_ 2048
#define D_ 1024
#define H_ 16
#define HD_ 64
#define MTOT (B_*N_)   // 8192
#define CH_ 16         // scan chunk size
#define NCH_ (N_/CH_)  // 128

typedef __attribute__((ext_vector_type(8))) short short8v;
typedef __attribute__((ext_vector_type(4))) float f32x4;

// fast sigmoid: raw v_rcp_f32 (~1 ulp), avoids IEEE div sequence on the serial chain
__device__ __forceinline__ float fsig(float x){
  return __builtin_amdgcn_rcpf(1.0f + __expf(-x));
}

// ---------------- cast x -> bf16 (vectorized) ----------------
__global__ void k_cast_bf16(const float* __restrict__ in, __hip_bfloat16* __restrict__ out, int n4){
  int i = blockIdx.x*256 + threadIdx.x;
  if (i >= n4) return;
  float4 vv = ((const float4*)in)[i];
  __hip_bfloat16 b0 = __float2bfloat16(vv.x), b1 = __float2bfloat16(vv.y),
                 b2 = __float2bfloat16(vv.z), b3 = __float2bfloat16(vv.w);
  ushort4 o;
  o.x = *(const unsigned short*)&b0; o.y = *(const unsigned short*)&b1;
  o.z = *(const unsigned short*)&b2; o.w = *(const unsigned short*)&b3;
  ((ushort4*)out)[i] = o;
}

// ---------------- transpose + cast: out[c][r] = in[r][c] ----------------
__global__ void k_transpose_cast(const float* __restrict__ in, __hip_bfloat16* __restrict__ out,
                                 int R, int C){
  __shared__ float tile[64][65];
  int r0 = blockIdx.y*64, c0 = blockIdx.x*64;
  int tid = threadIdx.x;
  #pragma unroll
  for (int i=0;i<16;i++){ int idx = tid + i*256; int rr = idx>>6, cc = idx&63;
    tile[rr][cc] = in[(size_t)(r0+rr)*C + (c0+cc)]; }
  __syncthreads();
  #pragma unroll
  for (int i=0;i<16;i++){ int idx = tid + i*256; int rr = idx>>6, cc = idx&63;
    out[(size_t)(c0+rr)*R + (r0+cc)] = __float2bfloat16(tile[cc][rr]); }
}

// ---------------- pack gate/lr weights: WgL[128][1024] = [Wg1^T ; Wlr^T ; 0] ----------------
__global__ void k_prep_wgl(const float* __restrict__ Wg1, const float* __restrict__ Wlr,
                           __hip_bfloat16* __restrict__ WgL){
  int idx = blockIdx.x*256 + threadIdx.x;   // 0..131071
  int r = idx >> 10, d = idx & 1023;
  float v = 0.f;
  if (r < 64) v = Wg1[(size_t)d*64 + r];
  else if (r < 80) v = Wlr[(size_t)d*16 + (r-64)];
  WgL[idx] = __float2bfloat16(v);
}

// ---------------- post: proj[8192][128] -> t1 bf16 (cols 0-63), lr = 0.01*sigmoid (cols 64-79) ----
__global__ void k_post_gl(const float* __restrict__ proj, __hip_bfloat16* __restrict__ t1,
                          float* __restrict__ lrout){
  int m = blockIdx.x*4 + (threadIdx.x>>6);
  int e = threadIdx.x & 63;
  float val = proj[(size_t)m*128 + e];
  t1[(size_t)m*64 + e] = __float2bfloat16(val);
  if (e < 16){
    float s = proj[(size_t)m*128 + 64 + e];
    lrout[(size_t)m*16 + e] = 0.01f*fsig(s);
  }
}

// ---------------- async global->LDS helper (16B per lane, dest = base + lane*16) ----------------
__device__ __forceinline__ void gl2lds16(const void* g, void* l){
  __builtin_amdgcn_global_load_lds((const __attribute__((address_space(1))) void*)g,
                                   (__attribute__((address_space(3))) void*)l, 16, 0, 0);
}

// ---------------- bf16 MFMA GEMM with global_load_lds staging ----------------
// LAYOUT 0: C[m*N+col] fp32. LAYOUT 2: fused QKV (N=3072) -> bf16 scatter [b][h][t][e],
// silu on q,k (t3<2).
template<int ACT, int LAYOUT>
__global__ __launch_bounds__(256,2) void k_gemm_bt2(
    const __hip_bfloat16* __restrict__ A, const __hip_bfloat16* __restrict__ BT,
    float* __restrict__ C, int M, int N, int K)
{
  __shared__ short As[128*32];
  __shared__ short Bs[128*32];
  const int n0 = blockIdx.x*128, m0 = blockIdx.y*128;
  const int tid = threadIdx.x, lane = tid & 63, wid = tid >> 6;
  const int wm = wid >> 1, wn = wid & 1;
  const short* Aps = (const short*)A;
  const short* Bps = (const short*)BT;
  f32x4 acc[4][4] = {};
  const int srow = wid*32 + (lane>>2);
  const int scol = (lane&3)*8;
  const size_t aoff0 = (size_t)(m0+srow)*K + scol;
  const size_t boff0 = (size_t)(n0+srow)*K + scol;
  short* lA = As + wid*1024;
  short* lB = Bs + wid*1024;
  const int row = lane & 15, kq = (lane >> 4)*8;
  for (int kk = 0; kk < K; kk += 32) {
    __syncthreads();
    gl2lds16(Aps + aoff0 + kk,                 lA);
    gl2lds16(Aps + aoff0 + (size_t)16*K + kk,  lA + 512);
    gl2lds16(Bps + boff0 + kk,                 lB);
    gl2lds16(Bps + boff0 + (size_t)16*K + kk,  lB + 512);
    __syncthreads();
    short8v af[4], bfr[4];
    #pragma unroll
    for (int i=0;i<4;i++) af[i]  = *(const short8v*)(As + (wm*64 + i*16 + row)*32 + kq);
    #pragma unroll
    for (int j=0;j<4;j++) bfr[j] = *(const short8v*)(Bs + (wn*64 + j*16 + row)*32 + kq);
    #pragma unroll
    for (int i=0;i<4;i++)
      #pragma unroll
      for (int j=0;j<4;j++)
        acc[i][j] = __builtin_amdgcn_mfma_f32_16x16x32_bf16(af[i], bfr[j], acc[i][j], 0, 0, 0);
  }
  #pragma unroll
  for (int i=0;i<4;i++){
    #pragma unroll
    for (int j=0;j<4;j++){
      int col = n0 + wn*64 + j*16 + (lane & 15);
      #pragma unroll
      for (int qq=0; qq<4; ++qq){
        int rowg = m0 + wm*64 + i*16 + (lane>>4)*4 + qq;
        float val = acc[i][j][qq];
        if (LAYOUT==0) {
          if (ACT==1) val = val*fsig(val);
          C[(size_t)rowg*N + col] = val;
        } else {
          const int t3 = col >> 10, cc2 = col & 1023;
          if (t3 < 2) val = val*fsig(val);   // silu on q,k; none on v
          size_t oidx = (size_t)t3*((size_t)MTOT*D_)
                      + ((((size_t)(rowg>>11))*16 + (cc2>>6))*(size_t)N_ + (size_t)(rowg & 2047))*64
                      + (size_t)(cc2 & 63);
          ((__hip_bfloat16*)C)[oidx] = __float2bfloat16(val);
        }
      }
    }
  }
}

// ---------------- helpers for chunked scan ----------------
__device__ __forceinline__ unsigned short bfr16(float x){
  __hip_bfloat16 b = __float2bfloat16(x);
  return *(unsigned short*)&b;
}

// ---------------- chunked fast-weight scan v13 ----------------
// Champion 3-barrier structure + (1) phase O moved into the B-window on waves1-3
// (QW/GQK/C13 double-buffered by chunk parity; O(c-1) hidden under B(c); epilogue O
// for the last chunk), (2) q/k/v consumed as bf16 (MFMA inputs bit-identical to v8;
// new rounding only on v in the error term and k in the W update).
__global__ __launch_bounds__(256,1) void k_scan13(
    const __hip_bfloat16* __restrict__ q, const __hip_bfloat16* __restrict__ k,
    const __hip_bfloat16* __restrict__ v, const float* __restrict__ lr,
    const float* __restrict__ w1i, const float* __restrict__ w3i,
    float* __restrict__ so)
{
  const int blk = blockIdx.x;            // 0..255
  const int bh  = blk >> 2;              // b*16+h
  const int sl  = blk & 3;               // e-slab
  const int b = bh >> 4, h = bh & 15;
  const int e0 = sl*16;
  const int tid = threadIdx.x, lane = tid & 63, wid = tid >> 6;
  const int tA = lane & 15, ks8 = (lane >> 4)*8;

  __shared__ __align__(16) __hip_bfloat16 Wb1[16*64];   // mirror [e][d], XOR-swizzled
  __shared__ __align__(16) __hip_bfloat16 Wb3[16*64];
  __shared__ __align__(16) float KW1e[256], KW3e[256];  // [e][t], swizzled 16B slots
  __shared__ __align__(16) float QW1[2][256], QW3[2][256];  // [par][t][e]
  __shared__ __align__(16) float GKK[256];              // [t][s]
  __shared__ __align__(16) float GQK[2][256];           // [par][t][s]
  __shared__ __align__(16) float C13[2][512];           // [par][s][e][{c1,c3}]
  __shared__ __align__(16) float kS[16][68];            // chunk-c k rows fp32 (+4 pad)

  const int we = tid & 15;
  const int wd = (tid >> 4) * 4;
  float w1r[4], w3r[4];
  {
    const float* w1p = w1i + (size_t)h*HD_*HD_ + e0 + we;
    const float* w3p = w3i + (size_t)h*HD_*HD_ + e0 + we;
    #pragma unroll
    for (int j=0;j<4;j++){ w1r[j] = w1p[(size_t)(wd+j)*64]; w3r[j] = w3p[(size_t)(wd+j)*64]; }
  }
  const int mir_off = we*128 + ((wd*2) ^ ((we&7)<<4));  // byte offset, 8B aligned
  auto write_mirrors = [&](){
    uint2 p1, p3;
    p1.x = (unsigned)bfr16(w1r[0]) | ((unsigned)bfr16(w1r[1])<<16);
    p1.y = (unsigned)bfr16(w1r[2]) | ((unsigned)bfr16(w1r[3])<<16);
    p3.x = (unsigned)bfr16(w3r[0]) | ((unsigned)bfr16(w3r[1])<<16);
    p3.y = (unsigned)bfr16(w3r[2]) | ((unsigned)bfr16(w3r[3])<<16);
    *(uint2*)((char*)Wb1 + mir_off) = p1;
    *(uint2*)((char*)Wb3 + mir_off) = p3;
  };
  write_mirrors();

  const short* kps = (const short*)(k + (size_t)bh*N_*64);
  const short* qps = (const short*)(q + (size_t)bh*N_*64);
  const __hip_bfloat16* vfb = v + (size_t)bh*N_*64;
  const float* lrp = lr + ((size_t)b*N_)*16 + h;
  float* sob = so + (((size_t)b*N_)*16 + h)*64 + e0;

  auto mir_read = [&](const __hip_bfloat16* Wm, int m)->short8v{
    return *(const short8v*)((const char*)Wm + tA*128 + (((m*32+ks8)*2) ^ ((tA&7)<<4)));
  };

  short8v pK0, pK1;                // waves1,3: k frags of current A-chunk
  short8v pQ0, pQ1;                // waves2,3: q frags
  float  vvr[16], lrr[16];         // wave0 lanes<16

  if (wid==1 || wid==3){
    pK0 = *(const short8v*)(kps + (size_t)tA*64 + ks8);
    pK1 = *(const short8v*)(kps + (size_t)tA*64 + 32 + ks8);
  }
  if (wid==2 || wid==3){
    pQ0 = *(const short8v*)(qps + (size_t)tA*64 + ks8);
    pQ1 = *(const short8v*)(qps + (size_t)tA*64 + 32 + ks8);
  }
  if (wid==0 && lane < 16) {
    #pragma unroll
    for (int t=0;t<CH_;++t){
      vvr[t] = __bfloat162float(vfb[(size_t)t*64 + e0 + lane]);
      lrr[t] = lrp[(size_t)t*16];
    }
  }
  __syncthreads();

  #pragma unroll 1
  for (int c = 0; c < NCH_; ++c) {
    const int t0 = c*CH_;
    const int par = c & 1;

    // ---- phase A: MFMA products from prefetched bf16 frags (waves 1-3) ----
    if (wid == 1) {
      // stage chunk-c k rows as fp32 for phase C (bf16 -> f32 is a shift)
      float kf_[16];
      #pragma unroll
      for (int j=0;j<4;j++){
        unsigned u = ((const unsigned*)&pK0)[j];
        kf_[2*j]   = __uint_as_float(u << 16);
        kf_[2*j+1] = __uint_as_float(u & 0xffff0000u);
      }
      #pragma unroll
      for (int j=0;j<4;j++){
        unsigned u = ((const unsigned*)&pK1)[j];
        kf_[8+2*j]   = __uint_as_float(u << 16);
        kf_[8+2*j+1] = __uint_as_float(u & 0xffff0000u);
      }
      f32x4 s0 = {kf_[0],kf_[1],kf_[2],kf_[3]};   *(f32x4*)&kS[tA][ks8]      = s0;
      f32x4 s1 = {kf_[4],kf_[5],kf_[6],kf_[7]};   *(f32x4*)&kS[tA][ks8+4]    = s1;
      f32x4 s2 = {kf_[8],kf_[9],kf_[10],kf_[11]}; *(f32x4*)&kS[tA][32+ks8]   = s2;
      f32x4 s3 = {kf_[12],kf_[13],kf_[14],kf_[15]};*(f32x4*)&kS[tA][32+ks8+4]= s3;
      const int slot = (((lane>>4)*4) ^ (((tA>>1)&3)<<2));
      f32x4 acc = {};
      acc = __builtin_amdgcn_mfma_f32_16x16x32_bf16(pK0, mir_read(Wb1,0), acc, 0,0,0);
      acc = __builtin_amdgcn_mfma_f32_16x16x32_bf16(pK1, mir_read(Wb1,1), acc, 0,0,0);
      *(f32x4*)&KW1e[tA*16 + slot] = acc;
      f32x4 ac3 = {};
      ac3 = __builtin_amdgcn_mfma_f32_16x16x32_bf16(pK0, mir_read(Wb3,0), ac3, 0,0,0);
      ac3 = __builtin_amdgcn_mfma_f32_16x16x32_bf16(pK1, mir_read(Wb3,1), ac3, 0,0,0);
      *(f32x4*)&KW3e[tA*16 + slot] = ac3;
    } else if (wid == 2) {
      f32x4 acc = {};
      acc = __builtin_amdgcn_mfma_f32_16x16x32_bf16(pQ0, mir_read(Wb1,0), acc, 0,0,0);
      acc = __builtin_amdgcn_mfma_f32_16x16x32_bf16(pQ1, mir_read(Wb1,1), acc, 0,0,0);
      #pragma unroll
      for (int qq=0;qq<4;++qq) QW1[par][((lane>>4)*4+qq)*16 + tA] = acc[qq];   // t-major
      f32x4 ac3 = {};
      ac3 = __builtin_amdgcn_mfma_f32_16x16x32_bf16(pQ0, mir_read(Wb3,0), ac3, 0,0,0);
      ac3 = __builtin_amdgcn_mfma_f32_16x16x32_bf16(pQ1, mir_read(Wb3,1), ac3, 0,0,0);
      #pragma unroll
      for (int qq=0;qq<4;++qq) QW3[par][((lane>>4)*4+qq)*16 + tA] = ac3[qq];
    } else if (wid == 3) {
      f32x4 acc = {};
      acc = __builtin_amdgcn_mfma_f32_16x16x32_bf16(pK0, pK0, acc, 0,0,0);
      acc = __builtin_amdgcn_mfma_f32_16x16x32_bf16(pK1, pK1, acc, 0,0,0);
      #pragma unroll
      for (int qq=0;qq<4;++qq) GKK[((lane>>4)*4+qq)*16 + tA] = acc[qq];
      f32x4 ac2 = {};
      ac2 = __builtin_amdgcn_mfma_f32_16x16x32_bf16(pQ0, pK0, ac2, 0,0,0);
      ac2 = __builtin_amdgcn_mfma_f32_16x16x32_bf16(pQ1, pK1, ac2, 0,0,0);
      #pragma unroll
      for (int qq=0;qq<4;++qq) GQK[par][((lane>>4)*4+qq)*16 + tA] = ac2[qq];
    }
    __syncthreads();   // bar1: A results visible

    // ---- phase B window: wave0 serial B(c); waves1-3 prefetch c+1 then O(c-1) ----
    const int tn0 = ((c+1 < NCH_) ? c+1 : c) * CH_;
    if (wid >= 1) {
      if (wid==1 || wid==3){
        pK0 = *(const short8v*)(kps + (size_t)(tn0+tA)*64 + ks8);
        pK1 = *(const short8v*)(kps + (size_t)(tn0+tA)*64 + 32 + ks8);
      }
      if (wid==2 || wid==3){
        pQ0 = *(const short8v*)(qps + (size_t)(tn0+tA)*64 + ks8);
        pQ1 = *(const short8v*)(qps + (size_t)(tn0+tA)*64 + 32 + ks8);
      }
      if (c > 0) {
        const int parp = par ^ 1;
        const int bt = t0 - CH_;
        const int p0 = tid - 64;        // 0..191
        #pragma unroll
        for (int rep=0; rep<2; ++rep){
          const int pp = p0 + rep*192;
          if (pp < 256){
            const int ot = pp >> 4, oe = pp & 15;
            float o1 = QW1[parp][ot*16+oe], o3 = QW3[parp][ot*16+oe];
            #pragma unroll
            for (int s = 0; s < CH_; ++s) {
              const float gl2 = GQK[parp][ot*16+s];
              const float2 cc = *(const float2*)&C13[parp][(s*16+oe)*2];
              const float g = (s <= ot) ? gl2 : 0.0f;
              o1 = fmaf(-g, cc.x, o1);
              o3 = fmaf(-g, cc.y, o3);
            }
            sob[(size_t)(bt+ot)*(H_*HD_) + oe] = (o1*fsig(o1))*o3;
          }
        }
      }
    } else if (lane < 16) {
      // issue c+1 v/lr loads (land during serial B)
      float vvn[16], lrn[16];
      #pragma unroll
      for (int t=0;t<CH_;++t){
        vvn[t] = __bfloat162float(vfb[(size_t)(tn0+t)*64 + e0 + lane]);
        lrn[t] = lrp[(size_t)(tn0+t)*16];
      }
      // preload this lane's KW rows (e = lane) into accumulators (undo slot swizzle)
      float a1[16], a3[16];
      const int swr = ((lane>>1)&3)<<2;
      #pragma unroll
      for (int i2=0;i2<4;i2++){
        f32x4 x1 = *(const f32x4*)&KW1e[lane*16 + ((i2*4) ^ swr)];
        f32x4 x3 = *(const f32x4*)&KW3e[lane*16 + ((i2*4) ^ swr)];
        a1[i2*4+0]=x1[0]; a1[i2*4+1]=x1[1]; a1[i2*4+2]=x1[2]; a1[i2*4+3]=x1[3];
        a3[i2*4+0]=x3[0]; a3[i2*4+1]=x3[1]; a3[i2*4+2]=x3[2]; a3[i2*4+3]=x3[3];
      }
      // GKK row pipeline (row t needed at token t; symmetric so row == column)
      f32x4 grow[3][4];
      #pragma unroll
      for (int i2=0;i2<4;i2++){
        grow[0][i2] = *(const f32x4*)&GKK[ 0 + i2*4];
        grow[1][i2] = *(const f32x4*)&GKK[16 + i2*4];
        grow[2][i2] = *(const f32x4*)&GKK[32 + i2*4];
      }
      #pragma unroll
      for (int t = 0; t < CH_; ++t) {
        const float h1 = a1[t], h3 = a3[t];   // fully corrected by eager updates
        const float sg = fsig(h1);
        const float s1 = h1*sg;
        const float er = fmaf(s1, h3, -vvr[t]);
        const float ds = sg*fmaf(h1, 1.0f - sg, 1.0f);
        const float lt = lrr[t];
        float2 cc; cc.x = lt*(er*h3*ds); cc.y = lt*(er*s1);
        *(float2*)&C13[par][(t*16+lane)*2] = cc;
        // eager: push correction of token t into all future accumulators
        #pragma unroll
        for (int t2 = t+1; t2 < CH_; ++t2) {
          const float g = grow[t%3][t2>>2][t2&3];
          a1[t2] = fmaf(-g, cc.x, a1[t2]);
          a3[t2] = fmaf(-g, cc.y, a3[t2]);
        }
        if (t + 3 < CH_) {   // refill consumed slot with row t+3 (used 3 tokens later)
          #pragma unroll
          for (int i2=0;i2<4;i2++) grow[(t+3)%3][i2] = *(const f32x4*)&GKK[(t+3)*16 + i2*4];
        }
      }
      #pragma unroll
      for (int t=0;t<CH_;++t){ vvr[t]=vvn[t]; lrr[t]=lrn[t]; }
    }
    __syncthreads();   // bar2: C13[par] visible

    // ---- phase C: rank-16 W update (k rows from LDS) + rewrite mirror ----
    #pragma unroll
    for (int s = 0; s < CH_; ++s) {
      const float2 cc = *(const float2*)&C13[par][(s*16+we)*2];
      const float4 ks = *(const float4*)&kS[s][wd];
      w1r[0] = fmaf(-ks.x, cc.x, w1r[0]); w1r[1] = fmaf(-ks.y, cc.x, w1r[1]);
      w1r[2] = fmaf(-ks.z, cc.x, w1r[2]); w1r[3] = fmaf(-ks.w, cc.x, w1r[3]);
      w3r[0] = fmaf(-ks.x, cc.y, w3r[0]); w3r[1] = fmaf(-ks.y, cc.y, w3r[1]);
      w3r[2] = fmaf(-ks.z, cc.y, w3r[2]); w3r[3] = fmaf(-ks.w, cc.y, w3r[3]);
    }
    write_mirrors();
    __syncthreads();   // bar3: mirror ready for A(c+1)
  }

  // ---- epilogue: O for the final chunk ----
  if (wid >= 1) {
    const int parp = (NCH_-1) & 1;
    const int bt = (NCH_-1)*CH_;
    const int p0 = tid - 64;
    #pragma unroll
    for (int rep=0; rep<2; ++rep){
      const int pp = p0 + rep*192;
      if (pp < 256){
        const int ot = pp >> 4, oe = pp & 15;
        float o1 = QW1[parp][ot*16+oe], o3 = QW3[parp][ot*16+oe];
        #pragma unroll
        for (int s = 0; s < CH_; ++s) {
          const float gl2 = GQK[parp][ot*16+s];
          const float2 cc = *(const float2*)&C13[parp][(s*16+oe)*2];
          const float g = (s <= ot) ? gl2 : 0.0f;
          o1 = fmaf(-g, cc.x, o1);
          o3 = fmaf(-g, cc.y, o3);
        }
        sob[(size_t)(bt+ot)*(H_*HD_) + oe] = (o1*fsig(o1))*o3;
      }
    }
  }
}

// ---------------- grouped RMSNorm * norm_w * sigmoid(gate) -> bf16 y ----------------
__global__ void k_norm_gate(const float* __restrict__ so, const float* __restrict__ gate,
                            const float* __restrict__ nw, __hip_bfloat16* __restrict__ y)
{
  int idx = blockIdx.x*4 + (threadIdx.x>>6);  // (b*N+t)*16+h
  int e = threadIdx.x & 63;
  float o = so[(size_t)idx*64 + e];
  float ss = o*o;
  #pragma unroll
  for (int m=32; m>=1; m>>=1) ss += __shfl_xor(ss, m, 64);
  float rms = rsqrtf(ss*(1.0f/64.0f) + 1e-6f);
  int hh = idx & 15;
  size_t bn = (size_t)(idx >> 4);
  int d = hh*64 + e;
  float g = gate[bn*1024 + d];
  float val = o*rms*nw[d] * fsig(g);
  y[bn*1024 + d] = __float2bfloat16(val);
}

extern "C" void kernel_launch(void* const* d_in, const int* in_sizes, int n_in,
                              void* d_out, int out_size, void* d_ws, size_t ws_size,
                              hipStream_t stream)
{
  const float* x   = (const float*)d_in[0];
  const float* Wq  = (const float*)d_in[1];
  const float* Wk  = (const float*)d_in[2];
  const float* Wv  = (const float*)d_in[3];
  const float* Wo  = (const float*)d_in[4];
  const float* w1i = (const float*)d_in[5];
  const float* w3i = (const float*)d_in[6];
  const float* Wlr = (const float*)d_in[7];
  const float* nw  = (const float*)d_in[8];
  const float* Wg1 = (const float*)d_in[9];
  const float* Wg2 = (const float*)d_in[10];
  float* out = (float*)d_out;

  char* p = (char*)d_ws;
  auto take = [&](size_t bytes)->void*{ void* r = (void*)p; p += (bytes + 255) & ~(size_t)255; return r; };
  __hip_bfloat16* xb    = (__hip_bfloat16*)take((size_t)MTOT*D_*2);
  __hip_bfloat16* WqkvT = (__hip_bfloat16*)take((size_t)3*D_*D_*2);   // [Wq^T ; Wk^T ; Wv^T]
  __hip_bfloat16* Wot   = (__hip_bfloat16*)take((size_t)D_*D_*2);
  __hip_bfloat16* Wg2t  = (__hip_bfloat16*)take((size_t)D_*HD_*2);
  __hip_bfloat16* WgL   = (__hip_bfloat16*)take((size_t)128*D_*2);
  __hip_bfloat16* t1b   = (__hip_bfloat16*)take((size_t)MTOT*HD_*2);
  float* projt = (float*)take((size_t)MTOT*128*4);
  __hip_bfloat16* qb = (__hip_bfloat16*)take((size_t)MTOT*D_*2);  // q,k,v contiguous bf16
  __hip_bfloat16* kb = (__hip_bfloat16*)take((size_t)MTOT*D_*2);
  __hip_bfloat16* vb = (__hip_bfloat16*)take((size_t)MTOT*D_*2);
  float* lrb = (float*)take((size_t)MTOT*H_*4);
  float* sob = (float*)take((size_t)MTOT*D_*4);
  __hip_bfloat16* yb = (__hip_bfloat16*)take((size_t)MTOT*D_*2);

  k_cast_bf16<<<MTOT*D_/4/256, 256, 0, stream>>>(x, xb, MTOT*D_/4);
  k_transpose_cast<<<dim3(16,16), 256, 0, stream>>>(Wq, WqkvT,             D_, D_);
  k_transpose_cast<<<dim3(16,16), 256, 0, stream>>>(Wk, WqkvT + D_*D_,     D_, D_);
  k_transpose_cast<<<dim3(16,16), 256, 0, stream>>>(Wv, WqkvT + 2*D_*D_,   D_, D_);
  k_transpose_cast<<<dim3(16,16), 256, 0, stream>>>(Wo, Wot, D_, D_);
  k_transpose_cast<<<dim3(16,1),  256, 0, stream>>>(Wg2, Wg2t, HD_, D_);
  k_prep_wgl<<<512, 256, 0, stream>>>(Wg1, Wlr, WgL);
  // gate bottleneck + lr head in one GEMM: proj = x @ [Wg1 | Wlr | 0]
  k_gemm_bt2<0,0><<<dim3(1,64), 256, 0, stream>>>(xb, WgL, projt, MTOT, 128, D_);
  k_post_gl<<<MTOT/4, 256, 0, stream>>>(projt, t1b, lrb);
  // fused q|k|v projection: one N=3072 GEMM, silu on q,k, bf16 scatter to [b][h][t][e]
  k_gemm_bt2<1,2><<<dim3(24,64), 256, 0, stream>>>(xb, WqkvT, (float*)qb, MTOT, 3*D_, D_);
  // gate pre-activation into d_out (free scratch until final GEMM)
  k_gemm_bt2<0,0><<<dim3(8,64), 256, 0, stream>>>(t1b, Wg2t, out, MTOT, D_, HD_);
  k_scan13<<<256, 256, 0, stream>>>(qb, kb, vb, lrb, w1i, w3i, sob);
  k_norm_gate<<<MTOT*H_/4, 256, 0, stream>>>(sob, out, nw, yb);
  k_gemm_bt2<0,0><<<dim3(8,64), 256, 0, stream>>>(yb, Wot, out, MTOT, D_, D_);
}